// Round 3
// baseline (8149.850 us; speedup 1.0000x reference)
//
#include <hip/hip_runtime.h>
#include <hip/hip_cooperative_groups.h>
#include <math.h>
#include <string.h>
#include <utility>
#include <initializer_list>

namespace cg = cooperative_groups;

// Problem constants
#define B_   4096
#define D_   256
#define H_   266
#define T_   51
#define S_   50
#define HP   320        // padded row stride (fp32 activations), = 5*BK
#define EPSF 1e-5f

typedef __bf16 bf16_t;
typedef __bf16 bf16x8 __attribute__((ext_vector_type(8)));
typedef float  f32x4  __attribute__((ext_vector_type(4)));

// MFMA GEMM tile config: block 64x64, 4 waves (2x2), each wave 32x32 (2x2 MFMA frags)
#define BM 64
#define BN 64
#define BK 64
#define LDST 72   // LDS row stride in bf16 (144 B: 16B-aligned, bank-skewed)

struct Job {
  int kind;                                           // 0 gemm, 1 wconv, 2 v0-fin
  const float* A; int lda; int Ka;                    // gemm: A MxKa fp32 | wconv: in | fin: yraw
  const float* g; const float* be;                    // BN-on-A params
  const float* asum; const float* asq;
  int bnA;
  const bf16_t* Wt; int ldw;                          // gemm: N x ldw bf16 (zero-padded)
  const float* bias;
  const float* trow; const float* tg; int tidx;       // optional bias += tg[tidx]*trow[col]; tg also hi/sq
  float* C; int ldc; int N; int relu;                 // wconv: C=out(bf16*), lda=K, ldc=N, ldw=Kp, Ka=total
  float* ssum; float* ssq;
  int mode;                                           // 0 store; 1 alpha-update; 2 grad-accum
  const float* xc; const float* xi; const float* law;
  float* xn; float* vacc;
};

struct Phase { int njobs; int total; int jidx[8]; int tcnt[8]; };

__device__ __forceinline__ void load16(const float* p, float* a) {
  const float4* q = (const float4*)p;
  float4 v0 = q[0], v1 = q[1], v2 = q[2], v3 = q[3];
  a[0]=v0.x; a[1]=v0.y; a[2]=v0.z;  a[3]=v0.w;
  a[4]=v1.x; a[5]=v1.y; a[6]=v1.z;  a[7]=v1.w;
  a[8]=v2.x; a[9]=v2.y; a[10]=v2.z; a[11]=v2.w;
  a[12]=v3.x; a[13]=v3.y; a[14]=v3.z; a[15]=v3.w;
}

__device__ void run_tile(const Job& j, int u, float invB) {
  __shared__ bf16_t As[BM][LDST];
  __shared__ bf16_t Ws[BN][LDST];
  __shared__ float sc[HP], sh[HP];

  const int cN = (j.N + BN - 1) >> 6;
  const int r0 = (u / cN) * BM;
  const int c0 = (u % cN) * BN;

  const int tid = threadIdx.x;

  // BN scale/shift for A columns; zero-fill padding (garbage -> 0; NaN killed by fmax).
  if (j.bnA) {
    for (int k = tid; k < HP; k += 256) {
      if (k < j.Ka) {
        float mu  = j.asum[k] * invB;
        float var = j.asq[k] * invB - mu * mu;
        float s   = j.g[k] * rsqrtf(var + EPSF);
        sc[k] = s; sh[k] = j.be[k] - mu * s;
      } else { sc[k] = 0.f; sh[k] = 0.f; }
    }
  }

  const int wave = tid >> 6;
  const int lane = tid & 63;
  const int wr = (wave >> 1) * 32;
  const int wc = (wave & 1) * 32;
  const int l16 = lane & 15;
  const int lk8 = (lane >> 4) * 8;

  f32x4 acc[2][2] = {};

  const int arow = tid >> 2;          // 0..63
  const int kseg = (tid & 3) * 16;    // 0,16,32,48

  const int niter = (j.Ka + BK - 1) / BK;   // 4 (K=256) or 5 (K=266, lda=320)

  const float*  Abase = j.A + (size_t)(r0 + arow) * j.lda + kseg;
  const int     crow  = c0 + arow;
  const bf16_t* Wbase = j.Wt + (size_t)crow * j.ldw + kseg;
  const bool    wok   = crow < j.N;

  float a16[16];
  uint4 wv0 = make_uint4(0,0,0,0), wv1 = make_uint4(0,0,0,0);

  load16(Abase, a16);
  if (wok) {
    const uint4* q = (const uint4*)Wbase;
    wv0 = q[0]; wv1 = q[1];
  }

  for (int it = 0; it < niter; ++it) {
    const int kb = it * BK + kseg;

    __syncthreads();   // prior tile/iter LDS reads done (also covers sc/sh init)

    bf16x8 p0, p1;
    if (j.bnA) {
      #pragma unroll
      for (int i = 0; i < 8; ++i)
        p0[i] = (bf16_t)fmaxf(fmaf(a16[i], sc[kb + i], sh[kb + i]), 0.f);
      #pragma unroll
      for (int i = 0; i < 8; ++i)
        p1[i] = (bf16_t)fmaxf(fmaf(a16[8 + i], sc[kb + 8 + i], sh[kb + 8 + i]), 0.f);
    } else {
      #pragma unroll
      for (int i = 0; i < 8; ++i) {
        float t = (kb + i < j.Ka) ? a16[i] : 0.f;
        p0[i] = (bf16_t)t;
      }
      #pragma unroll
      for (int i = 0; i < 8; ++i) {
        float t = (kb + 8 + i < j.Ka) ? a16[8 + i] : 0.f;
        p1[i] = (bf16_t)t;
      }
    }
    *(bf16x8*)&As[arow][kseg]     = p0;
    *(bf16x8*)&As[arow][kseg + 8] = p1;
    *(uint4*)&Ws[arow][kseg]      = wv0;
    *(uint4*)&Ws[arow][kseg + 8]  = wv1;

    __syncthreads();

    if (it + 1 < niter) {
      load16(Abase + (size_t)(it + 1) * BK, a16);
      if (wok) {
        const uint4* q = (const uint4*)(Wbase + (size_t)(it + 1) * BK);
        wv0 = q[0]; wv1 = q[1];
      }
    }

    bf16x8 af[2][2], bfr[2][2];
    #pragma unroll
    for (int mi = 0; mi < 2; ++mi)
      #pragma unroll
      for (int kk = 0; kk < 2; ++kk)
        af[mi][kk] = *(const bf16x8*)&As[wr + mi*16 + l16][kk*32 + lk8];
    #pragma unroll
    for (int ni = 0; ni < 2; ++ni)
      #pragma unroll
      for (int kk = 0; kk < 2; ++kk)
        bfr[ni][kk] = *(const bf16x8*)&Ws[wc + ni*16 + l16][kk*32 + lk8];
    #pragma unroll
    for (int kk = 0; kk < 2; ++kk)
      #pragma unroll
      for (int mi = 0; mi < 2; ++mi)
        #pragma unroll
        for (int ni = 0; ni < 2; ++ni)
          acc[mi][ni] = __builtin_amdgcn_mfma_f32_16x16x32_bf16(af[mi][kk], bfr[ni][kk], acc[mi][ni], 0, 0, 0);
  }

  // ---- epilogue ----
  float tb = j.trow ? j.tg[j.tidx] : 0.f;
  float vv[2][2][4];
  #pragma unroll
  for (int ni = 0; ni < 2; ++ni) {
    int col = c0 + wc + ni*16 + l16;
    bool cok = col < j.N;
    float bias = cok ? j.bias[col] : 0.f;
    if (j.trow && cok) bias = fmaf(tb, j.trow[col], bias);
    #pragma unroll
    for (int mi = 0; mi < 2; ++mi)
      #pragma unroll
      for (int r = 0; r < 4; ++r) {
        float v = acc[mi][ni][r] + bias;
        if (j.relu) v = fmaxf(v, 0.f);
        vv[mi][ni][r] = v;
      }
  }

  if (j.mode == 0) {
    #pragma unroll
    for (int ni = 0; ni < 2; ++ni) {
      int col = c0 + wc + ni*16 + l16;
      bool cok = col < j.N;
      float s = 0.f, q = 0.f;
      #pragma unroll
      for (int mi = 0; mi < 2; ++mi)
        #pragma unroll
        for (int r = 0; r < 4; ++r) {
          float v = vv[mi][ni][r];
          int row = r0 + wr + mi*16 + ((lane >> 4) << 2) + r;
          if (cok) j.C[(size_t)row * j.ldc + col] = v;
          s += v; q += v * v;
        }
      if (j.ssum) {
        s += __shfl_xor(s, 16); q += __shfl_xor(q, 16);
        s += __shfl_xor(s, 32); q += __shfl_xor(q, 32);
        if (lane < 16) {
          int col2 = c0 + wc + ni*16 + lane;
          if (col2 < j.N) { atomicAdd(&j.ssum[col2], s); atomicAdd(&j.ssq[col2], q); }
        }
      }
    }
  } else {
    float hi = j.tg[j.tidx + 1] - j.tg[j.tidx];
    float sq = sqrtf(hi);
    #pragma unroll
    for (int mi = 0; mi < 2; ++mi) {
      #pragma unroll
      for (int r = 0; r < 4; ++r) {
        int row = r0 + wr + mi*16 + ((lane >> 4) << 2) + r;
        float part = 0.f;
        #pragma unroll
        for (int ni = 0; ni < 2; ++ni) {
          int col = c0 + wc + ni*16 + l16;
          size_t off = (size_t)row * D_ + col;
          float v = vv[mi][ni][r];
          if (j.mode == 1) {
            float xcv = j.xc[off];
            float xiv = j.xi[off];
            float lw  = j.law[col];
            j.xn[off] = xcv + v * hi + sq * xiv;
            float df = xcv - lw;
            part += df * df + v * v;
          } else {
            part += v * j.xi[off];
          }
        }
        part += __shfl_xor(part, 1); part += __shfl_xor(part, 2);
        part += __shfl_xor(part, 4); part += __shfl_xor(part, 8);
        if (l16 == 0)
          atomicAdd(&j.vacc[row], (j.mode == 1) ? -0.5f * hi * part : sq * part);
      }
    }
  }
}

__global__ __launch_bounds__(256, 3) void scan_all(const Job* __restrict__ jobs,
                                                   const Phase* __restrict__ phases,
                                                   int nphase, float invB) {
  cg::grid_group grid = cg::this_grid();
  const int tid = threadIdx.x;
  for (int p = 0; p < nphase; ++p) {
    const Phase& ph = phases[p];
    for (int t = blockIdx.x; t < ph.total; t += gridDim.x) {
      int k = 0, off = t;
      while (k + 1 < ph.njobs && off >= ph.tcnt[k]) { off -= ph.tcnt[k]; ++k; }
      const Job& j = jobs[ph.jidx[k]];
      if (j.kind == 0) {
        run_tile(j, off, invB);
      } else if (j.kind == 1) {
        // wconv tile: 65536 elems. out[s][n][kk] = in[s][kk][n], zero-pad kk>=K.
        const int base = off << 16;
        const int tot  = j.Ka;
        const int end  = (base + 65536 < tot) ? base + 65536 : tot;
        const float* in = j.A;
        bf16_t* outp = (bf16_t*)j.C;
        const int K = j.lda, N = j.ldc, Kp = j.ldw;
        for (int idx = base + tid; idx < end; idx += 256) {
          int kk = idx % Kp; int rest = idx / Kp; int n = rest % N; int s = rest / N;
          float val = (kk < K) ? in[((size_t)s * K + kk) * N + n] : 0.f;
          outp[idx] = (bf16_t)val;
        }
      } else {
        // v0 finalize: v[r] = relu(BN1(yraw[r]))
        int r = off * 256 + tid;
        float mu  = j.asum[0] * invB;
        float var = j.asq[0] * invB - mu * mu;
        float tt  = j.g[0] * (j.A[r] - mu) * rsqrtf(var + EPSF) + j.be[0];
        j.C[r] = fmaxf(tt, 0.f);
      }
    }
    if (p + 1 < nphase) grid.sync();
  }
}

struct Tab { Job jobs[272]; Phase phases[112]; };
static Tab h_tab;

extern "C" void kernel_launch(void* const* d_in, const int* in_sizes, int n_in,
                              void* d_out, int out_size, void* d_ws, size_t ws_size,
                              hipStream_t stream) {
  const float* x    = (const float*)d_in[0];
  const float* W1   = (const float*)d_in[1];
  const float* b1   = (const float*)d_in[2];
  const float* g1   = (const float*)d_in[3];
  const float* be1  = (const float*)d_in[4];
  const float* W2   = (const float*)d_in[5];
  const float* b2   = (const float*)d_in[6];
  const float* g2   = (const float*)d_in[7];
  const float* be2  = (const float*)d_in[8];
  const float* W3   = (const float*)d_in[9];
  const float* b3   = (const float*)d_in[10];
  const float* vW1  = (const float*)d_in[11];
  const float* vb1  = (const float*)d_in[12];
  const float* vg1  = (const float*)d_in[13];
  const float* vbe1 = (const float*)d_in[14];
  const float* vW2  = (const float*)d_in[15];
  const float* vb2  = (const float*)d_in[16];
  const float* vg2  = (const float*)d_in[17];
  const float* vbe2 = (const float*)d_in[18];
  const float* vW3  = (const float*)d_in[19];
  const float* vb3  = (const float*)d_in[20];
  const float* vg3  = (const float*)d_in[21];
  const float* vbe3 = (const float*)d_in[22];
  const float* aW1  = (const float*)d_in[23];
  const float* ab1  = (const float*)d_in[24];
  const float* aW2  = (const float*)d_in[25];
  const float* ab2  = (const float*)d_in[26];
  const float* law  = (const float*)d_in[27];
  const float* tg   = (const float*)d_in[28];
  const float* xi   = (const float*)d_in[29];

  float* out    = (float*)d_out;
  float* v_out  = out;
  float* xf_out = out + B_;
  float* path   = out + B_ + (size_t)B_ * D_;

  float* ws   = (float*)d_ws;
  float* h1   = ws;
  float* h2   = h1 + (size_t)B_ * HP;
  float* ah   = h2 + (size_t)B_ * HP;
  float* yraw = ah + (size_t)B_ * HP;
  float* stats = yraw + B_;
  const int NSLOT = 2 * S_ + 3;
  float* tabf = stats + (size_t)NSLOT * 2 * HP;

  Tab* d_tab = (Tab*)tabf;
  bf16_t* wbuf = (bf16_t*)((char*)tabf + ((sizeof(Tab) + 255) & ~(size_t)255));
  bf16_t* W1t  = wbuf;                                   // [50][266][256]
  bf16_t* W2t  = W1t + (size_t)S_ * H_ * 256;            // [50][266][320]
  bf16_t* W3t  = W2t + (size_t)S_ * H_ * 320;            // [50][256][320]
  bf16_t* aW1t = W3t + (size_t)S_ * 256 * 320;           // [266][256]
  bf16_t* aW2t = aW1t + (size_t)H_ * 256;                // [256][320]
  bf16_t* vW1t = aW2t + (size_t)256 * 320;               // [266][256]
  bf16_t* vW2t = vW1t + (size_t)H_ * 256;                // [266][320]
  bf16_t* vW3t = vW2t + (size_t)H_ * 320;                // [1][320]

  auto ssum = [&](int s) { return stats + (size_t)s * 2 * HP; };
  auto ssq  = [&](int s) { return stats + (size_t)s * 2 * HP + HP; };

  const float invB = 1.0f / (float)B_;

  // ---------- build job/phase tables ----------
  memset(&h_tab, 0, sizeof(h_tab));
  int nj = 0, np = 0;

  auto wjob = [&](const float* in, bf16_t* outp, int K, int N, int Kp, int total) -> int {
    Job j{}; j.kind = 1; j.A = in; j.C = (float*)outp;
    j.lda = K; j.ldc = N; j.ldw = Kp; j.Ka = total;
    h_tab.jobs[nj] = j; return nj++;
  };
  auto gjob = [&](const float* A, int lda, int Ka,
                  const float* g, const float* be, const float* as, const float* aq, int bnA,
                  const bf16_t* Wt, int ldw, const float* bias,
                  const float* trow, int tidx,
                  float* C, int ldc, int N, int relu,
                  float* su, float* sq2, int mode,
                  const float* xc, const float* xii, const float* lw, float* xnp) -> int {
    Job j{}; j.kind = 0;
    j.A = A; j.lda = lda; j.Ka = Ka; j.g = g; j.be = be; j.asum = as; j.asq = aq; j.bnA = bnA;
    j.Wt = Wt; j.ldw = ldw; j.bias = bias; j.trow = trow; j.tg = tg; j.tidx = tidx;
    j.C = C; j.ldc = ldc; j.N = N; j.relu = relu; j.ssum = su; j.ssq = sq2; j.mode = mode;
    j.xc = xc; j.xi = xii; j.law = lw; j.xn = xnp; j.vacc = v_out;
    h_tab.jobs[nj] = j; return nj++;
  };
  auto addPhase = [&](std::initializer_list<std::pair<int,int>> items) {
    Phase p{};
    for (auto it = items.begin(); it != items.end(); ++it) {
      p.jidx[p.njobs] = it->first; p.tcnt[p.njobs] = it->second;
      p.total += it->second; p.njobs++;
    }
    h_tab.phases[np++] = p;
  };
  auto wt = [](int total) { return (total + 65535) >> 16; };

  // wconv jobs
  int JW[8], WT[8];
  JW[0] = wjob(W1,       W1t,  256, H_,  256, S_ * H_ * 256);  WT[0] = wt(S_ * H_ * 256);
  JW[1] = wjob(W2,       W2t,  H_,  H_,  320, S_ * H_ * 320);  WT[1] = wt(S_ * H_ * 320);
  JW[2] = wjob(W3,       W3t,  H_,  256, 320, S_ * 256 * 320); WT[2] = wt(S_ * 256 * 320);
  JW[3] = wjob(aW1 + H_, aW1t, 256, H_,  256, H_ * 256);       WT[3] = wt(H_ * 256);
  JW[4] = wjob(aW2,      aW2t, H_,  256, 320, 256 * 320);      WT[4] = wt(256 * 320);
  JW[5] = wjob(vW1,      vW1t, 256, H_,  256, H_ * 256);       WT[5] = wt(H_ * 256);
  JW[6] = wjob(vW2,      vW2t, H_,  H_,  320, H_ * 320);       WT[6] = wt(H_ * 320);
  JW[7] = wjob(vW3,      vW3t, H_,  1,   320, 320);            WT[7] = wt(320);

  // v0 jobs
  int JV1 = gjob(x, D_, D_, nullptr, nullptr, nullptr, nullptr, 0,
                 vW1t, 256, vb1, nullptr, 0, h1, HP, H_, 0,
                 ssum(100), ssq(100), 0, nullptr, nullptr, nullptr, nullptr);
  int JV2 = gjob(h1, HP, H_, vg1, vbe1, ssum(100), ssq(100), 1,
                 vW2t, 320, vb2, nullptr, 0, h2, HP, H_, 0,
                 ssum(101), ssq(101), 0, nullptr, nullptr, nullptr, nullptr);
  int JV3 = gjob(h2, HP, H_, vg2, vbe2, ssum(101), ssq(101), 1,
                 vW3t, 320, vb3, nullptr, 0, yraw, 1, 1, 0,
                 ssum(102), ssq(102), 0, nullptr, nullptr, nullptr, nullptr);
  int JFIN;
  {
    Job j{}; j.kind = 2; j.A = yraw; j.g = vg3; j.be = vbe3;
    j.asum = ssum(102); j.asq = ssq(102); j.C = v_out;
    h_tab.jobs[nj] = j; JFIN = nj++;
  }

  // scan jobs
  int JA[S_], JB[S_], JC[S_], JE[S_], JD[S_];
  for (int i = 0; i < S_; ++i) {
    const float* xc   = path + (size_t)i * B_ * D_;
    float* xn         = path + (size_t)(i + 1) * B_ * D_;
    const float* xi_i = xi + (size_t)i * B_ * D_;
    const float* lw_i = law + (size_t)i * D_;

    JA[i] = gjob(xc, D_, D_, nullptr, nullptr, nullptr, nullptr, 0,
                 W1t + (size_t)i * H_ * 256, 256, b1 + (size_t)i * H_, nullptr, 0,
                 h1, HP, H_, 0, ssum(2 * i), ssq(2 * i), 0,
                 nullptr, nullptr, nullptr, nullptr);
    JB[i] = gjob(xc, D_, D_, nullptr, nullptr, nullptr, nullptr, 0,
                 aW1t, 256, ab1, aW1, i,
                 ah, HP, H_, 1, nullptr, nullptr, 0,
                 nullptr, nullptr, nullptr, nullptr);
    JC[i] = gjob(h1, HP, H_, g1 + (size_t)i * H_, be1 + (size_t)i * H_, ssum(2 * i), ssq(2 * i), 1,
                 W2t + (size_t)i * H_ * 320, 320, b2 + (size_t)i * H_, nullptr, 0,
                 h2, HP, H_, 0, ssum(2 * i + 1), ssq(2 * i + 1), 0,
                 nullptr, nullptr, nullptr, nullptr);
    JE[i] = gjob(ah, HP, H_, nullptr, nullptr, nullptr, nullptr, 0,
                 aW2t, 320, ab2, nullptr, i,
                 nullptr, 0, D_, 0, nullptr, nullptr, 1,
                 xc, xi_i, lw_i, xn);
    JD[i] = gjob(h2, HP, H_, g2 + (size_t)i * H_, be2 + (size_t)i * H_, ssum(2 * i + 1), ssq(2 * i + 1), 1,
                 W3t + (size_t)i * 256 * 320, 320, b3 + (size_t)i * D_, nullptr, i,
                 nullptr, 0, D_, 0, nullptr, nullptr, 2,
                 nullptr, xi_i, nullptr, nullptr);
  }

  // phases
  addPhase({{JW[0],WT[0]},{JW[1],WT[1]},{JW[2],WT[2]},{JW[3],WT[3]},
            {JW[4],WT[4]},{JW[5],WT[5]},{JW[6],WT[6]},{JW[7],WT[7]}});
  addPhase({{JV1,320}});
  addPhase({{JV2,320}});
  addPhase({{JV3,64}});
  for (int i = 0; i < S_; ++i) {
    if (i == 0) addPhase({{JA[0],320},{JB[0],320},{JFIN,16}});
    else        addPhase({{JA[i],320},{JB[i],320},{JD[i-1],256}});
    addPhase({{JC[i],320},{JE[i],256}});
  }
  addPhase({{JD[S_-1],256}});

  // ---------- enqueue ----------
  hipMemsetAsync(stats, 0, (size_t)NSLOT * 2 * HP * sizeof(float), stream);
  hipMemcpyAsync(path, x, (size_t)B_ * D_ * sizeof(float), hipMemcpyDeviceToDevice, stream);
  hipMemcpyAsync(d_tab, &h_tab, sizeof(Tab), hipMemcpyHostToDevice, stream);

  static int s_grid = 0;
  if (s_grid == 0) {
    int nb = 0;
    hipError_t e = hipOccupancyMaxActiveBlocksPerMultiprocessor(&nb, scan_all, 256, 0);
    if (e != hipSuccess || nb < 1) nb = 1;
    long g = (long)nb * 256;
    if (g > 896) g = 896;
    s_grid = (int)g;
  }

  const Job* d_jobs = d_tab->jobs;
  const Phase* d_phases = d_tab->phases;
  int np_arg = np;
  float invB_arg = invB;
  void* kargs[] = { (void*)&d_jobs, (void*)&d_phases, (void*)&np_arg, (void*)&invB_arg };
  hipLaunchCooperativeKernel(scan_all, dim3(s_grid), dim3(256), kargs, 0, stream);

  hipMemcpyAsync(xf_out, path + (size_t)S_ * B_ * D_,
                 (size_t)B_ * D_ * sizeof(float), hipMemcpyDeviceToDevice, stream);
}

// Round 4
// 2539.363 us; speedup vs baseline: 3.2094x; 3.2094x over previous
//
#include <hip/hip_runtime.h>
#include <math.h>
#include <string.h>

// Problem constants
#define B_   4096
#define D_   256
#define H_   266
#define T_   51
#define S_   50
#define HP   320        // padded row stride (fp32 activations), = 5*BK
#define EPSF 1e-5f

typedef __bf16 bf16_t;
typedef __bf16 bf16x8 __attribute__((ext_vector_type(8)));
typedef float  f32x4  __attribute__((ext_vector_type(4)));

// GEMM tile: block 64x64, 4 waves (2x2), each wave 32x32 (2x2 MFMA frags)
#define BM 64
#define BN 64
#define BK 64
#define LDST 72        // LDS row stride bf16 for gemm tiles

// fused x-step: 32-row strip per block, 128 blocks
#define FXT 128
#define LDX 264        // Xs stride (256 + 8)
#define LDH 328        // Hs stride (320 + 8)
#define SMEM_BYTES 37888   // max(gemm 20992, fused 16896+20992)

struct Job {
  int kind;            // 0 gemm tile, 2 v0-fin, 3 fused-x
  int lda, Ka, bnA, ldw, tidx, ldc, N, relu, mode, t0, _pad;
  const float *A, *g, *be, *asum, *asq, *bias, *bias2, *trow, *tg, *xi, *law;
  const bf16_t *Wt, *Wt2;
  float *C, *ssum, *ssq, *xn, *vacc;
};

struct Pack { Job j[6]; int njobs; float invB; };

__device__ __forceinline__ void load16(const float* p, float* a) {
  const float4* q = (const float4*)p;
  float4 v0 = q[0], v1 = q[1], v2 = q[2], v3 = q[3];
  a[0]=v0.x; a[1]=v0.y; a[2]=v0.z;  a[3]=v0.w;
  a[4]=v1.x; a[5]=v1.y; a[6]=v1.z;  a[7]=v1.w;
  a[8]=v2.x; a[9]=v2.y; a[10]=v2.z; a[11]=v2.w;
  a[12]=v3.x; a[13]=v3.y; a[14]=v3.z; a[15]=v3.w;
}

__device__ void run_tile(const Job& j, int u, float invB, char* smem) {
  bf16_t (*As)[LDST] = (bf16_t(*)[LDST])smem;
  bf16_t (*Ws)[LDST] = (bf16_t(*)[LDST])(smem + BM*LDST*2);
  float* sc = (float*)(smem + 2*BM*LDST*2);
  float* sh = sc + HP;

  const int cN = (j.N + BN - 1) >> 6;
  const int r0 = (u / cN) * BM;
  const int c0 = (u % cN) * BN;
  const int tid = threadIdx.x;

  if (j.bnA) {
    for (int k = tid; k < HP; k += 256) {
      if (k < j.Ka) {
        float mu  = j.asum[k] * invB;
        float var = j.asq[k] * invB - mu * mu;
        float s   = j.g[k] * rsqrtf(var + EPSF);
        sc[k] = s; sh[k] = j.be[k] - mu * s;
      } else { sc[k] = 0.f; sh[k] = 0.f; }
    }
  }

  const int wave = tid >> 6;
  const int lane = tid & 63;
  const int wr = (wave >> 1) * 32;
  const int wc = (wave & 1) * 32;
  const int l16 = lane & 15;
  const int lk8 = (lane >> 4) * 8;

  f32x4 acc[2][2] = {};

  const int arow = tid >> 2;          // 0..63
  const int kseg = (tid & 3) * 16;    // 0,16,32,48
  const int niter = (j.Ka + BK - 1) / BK;

  const float*  Abase = j.A + (size_t)(r0 + arow) * j.lda + kseg;
  const int     crow  = c0 + arow;
  const bf16_t* Wbase = j.Wt + (size_t)crow * j.ldw + kseg;
  const bool    wok   = crow < j.N;

  float a16[16];
  uint4 wv0 = make_uint4(0,0,0,0), wv1 = make_uint4(0,0,0,0);

  load16(Abase, a16);
  if (wok) {
    const uint4* q = (const uint4*)Wbase;
    wv0 = q[0]; wv1 = q[1];
  }

  for (int it = 0; it < niter; ++it) {
    const int kb = it * BK + kseg;

    __syncthreads();

    bf16x8 p0, p1;
    if (j.bnA) {
      #pragma unroll
      for (int i = 0; i < 8; ++i)
        p0[i] = (bf16_t)fmaxf(fmaf(a16[i], sc[kb + i], sh[kb + i]), 0.f);
      #pragma unroll
      for (int i = 0; i < 8; ++i)
        p1[i] = (bf16_t)fmaxf(fmaf(a16[8 + i], sc[kb + 8 + i], sh[kb + 8 + i]), 0.f);
    } else {
      #pragma unroll
      for (int i = 0; i < 8; ++i) {
        float t = (kb + i < j.Ka) ? a16[i] : 0.f;
        p0[i] = (bf16_t)t;
      }
      #pragma unroll
      for (int i = 0; i < 8; ++i) {
        float t = (kb + 8 + i < j.Ka) ? a16[8 + i] : 0.f;
        p1[i] = (bf16_t)t;
      }
    }
    *(bf16x8*)&As[arow][kseg]     = p0;
    *(bf16x8*)&As[arow][kseg + 8] = p1;
    *(uint4*)&Ws[arow][kseg]      = wv0;
    *(uint4*)&Ws[arow][kseg + 8]  = wv1;

    __syncthreads();

    if (it + 1 < niter) {
      load16(Abase + (size_t)(it + 1) * BK, a16);
      if (wok) {
        const uint4* q = (const uint4*)(Wbase + (size_t)(it + 1) * BK);
        wv0 = q[0]; wv1 = q[1];
      }
    }

    bf16x8 af[2][2], bfr[2][2];
    #pragma unroll
    for (int mi = 0; mi < 2; ++mi)
      #pragma unroll
      for (int kk = 0; kk < 2; ++kk)
        af[mi][kk] = *(const bf16x8*)&As[wr + mi*16 + l16][kk*32 + lk8];
    #pragma unroll
    for (int ni = 0; ni < 2; ++ni)
      #pragma unroll
      for (int kk = 0; kk < 2; ++kk)
        bfr[ni][kk] = *(const bf16x8*)&Ws[wc + ni*16 + l16][kk*32 + lk8];
    #pragma unroll
    for (int kk = 0; kk < 2; ++kk)
      #pragma unroll
      for (int mi = 0; mi < 2; ++mi)
        #pragma unroll
        for (int ni = 0; ni < 2; ++ni)
          acc[mi][ni] = __builtin_amdgcn_mfma_f32_16x16x32_bf16(af[mi][kk], bfr[ni][kk], acc[mi][ni], 0, 0, 0);
  }

  // ---- epilogue ----
  float vv[2][2][4];
  #pragma unroll
  for (int ni = 0; ni < 2; ++ni) {
    int col = c0 + wc + ni*16 + l16;
    bool cok = col < j.N;
    float bias = cok ? j.bias[col] : 0.f;
    #pragma unroll
    for (int mi = 0; mi < 2; ++mi)
      #pragma unroll
      for (int r = 0; r < 4; ++r) {
        float v = acc[mi][ni][r] + bias;
        if (j.relu) v = fmaxf(v, 0.f);
        vv[mi][ni][r] = v;
      }
  }

  if (j.mode == 0) {
    #pragma unroll
    for (int ni = 0; ni < 2; ++ni) {
      int col = c0 + wc + ni*16 + l16;
      bool cok = col < j.N;
      float s = 0.f, q = 0.f;
      #pragma unroll
      for (int mi = 0; mi < 2; ++mi)
        #pragma unroll
        for (int r = 0; r < 4; ++r) {
          float v = vv[mi][ni][r];
          int row = r0 + wr + mi*16 + ((lane >> 4) << 2) + r;
          if (cok) j.C[(size_t)row * j.ldc + col] = v;
          s += v; q += v * v;
        }
      if (j.ssum) {
        s += __shfl_xor(s, 16); q += __shfl_xor(q, 16);
        s += __shfl_xor(s, 32); q += __shfl_xor(q, 32);
        if (lane < 16) {
          int col2 = c0 + wc + ni*16 + lane;
          if (col2 < j.N) { atomicAdd(&j.ssum[col2], s); atomicAdd(&j.ssq[col2], q); }
        }
      }
    }
  } else {
    // mode 2: grad tile -> accumulate sq*sum(grad*xi) into vacc (N==256, all cols valid)
    float hi = j.tg[j.tidx + 1] - j.tg[j.tidx];
    float sq = sqrtf(hi);
    #pragma unroll
    for (int mi = 0; mi < 2; ++mi) {
      #pragma unroll
      for (int r = 0; r < 4; ++r) {
        int row = r0 + wr + mi*16 + ((lane >> 4) << 2) + r;
        float part = 0.f;
        #pragma unroll
        for (int ni = 0; ni < 2; ++ni) {
          int col = c0 + wc + ni*16 + l16;
          part += vv[mi][ni][r] * j.xi[(size_t)row * D_ + col];
        }
        part += __shfl_xor(part, 1); part += __shfl_xor(part, 2);
        part += __shfl_xor(part, 4); part += __shfl_xor(part, 8);
        if (l16 == 0) atomicAdd(&j.vacc[row], sq * part);
      }
    }
  }
}

// fused x-step: strip of 32 rows. h = relu(xc@aW1'+ab1+t*aW1row0); alpha = h@aW2+ab2;
// xn = xc + alpha*h + sq*xi ; vacc[row] -= 0.5*h*(sum(xc-law)^2 + sum(alpha^2))
__device__ void run_fused(const Job& j, int u, char* smem) {
  bf16_t (*Xs)[LDX] = (bf16_t(*)[LDX])smem;
  bf16_t (*Hs)[LDH] = (bf16_t(*)[LDH])(smem + 32*LDX*2);
  const int tid = threadIdx.x;
  const int r0 = u * 32;

  // stage xc strip -> bf16 LDS
  {
    int row = tid >> 3, seg = (tid & 7) * 32;
    const float* src = j.A + (size_t)(r0 + row) * D_ + seg;
    bf16_t* dst = &Xs[row][seg];
    #pragma unroll
    for (int c = 0; c < 4; ++c) {
      float4 v0 = ((const float4*)src)[2*c], v1 = ((const float4*)src)[2*c+1];
      bf16x8 pk;
      pk[0]=(bf16_t)v0.x; pk[1]=(bf16_t)v0.y; pk[2]=(bf16_t)v0.z; pk[3]=(bf16_t)v0.w;
      pk[4]=(bf16_t)v1.x; pk[5]=(bf16_t)v1.y; pk[6]=(bf16_t)v1.z; pk[7]=(bf16_t)v1.w;
      *(bf16x8*)(dst + c*8) = pk;
    }
  }
  __syncthreads();

  const int wave = tid >> 6, lane = tid & 63;
  const int l16 = lane & 15, lk8 = (lane >> 4) * 8;
  const int wc1 = wave * 16;
  const float t  = j.tg[j.tidx];
  const float hi = j.tg[j.tidx + 1] - t;

  // GEMM1: h strip (cols 0..319, valid < 266)
  for (int nc = 0; nc < 5; ++nc) {
    int col = nc*64 + wc1 + l16;
    int cr  = (col < H_) ? col : (H_ - 1);
    const bf16_t* wp = j.Wt + (size_t)cr * 256 + lk8;
    f32x4 acc[2] = {};
    #pragma unroll
    for (int kk = 0; kk < 8; ++kk) {
      bf16x8 bfv = *(const bf16x8*)(wp + kk*32);
      #pragma unroll
      for (int mi = 0; mi < 2; ++mi) {
        bf16x8 af = *(const bf16x8*)&Xs[mi*16 + l16][kk*32 + lk8];
        acc[mi] = __builtin_amdgcn_mfma_f32_16x16x32_bf16(af, bfv, acc[mi], 0, 0, 0);
      }
    }
    float bias = (col < H_) ? (j.bias[col] + t * j.trow[col]) : 0.f;
    #pragma unroll
    for (int mi = 0; mi < 2; ++mi)
      #pragma unroll
      for (int r = 0; r < 4; ++r) {
        float hv = fmaxf(acc[mi][r] + bias, 0.f);
        if (col >= H_) hv = 0.f;
        Hs[mi*16 + ((lane >> 4) << 2) + r][nc*64 + wc1 + l16] = (bf16_t)hv;
      }
  }
  __syncthreads();

  // GEMM2 + update (K = 288 covers 266 + zero-pad)
  const float sq = sqrtf(hi);
  float fp[2][4] = {};
  for (int nc = 0; nc < 4; ++nc) {
    int col = nc*64 + wc1 + l16;
    const bf16_t* wp = j.Wt2 + (size_t)col * 320 + lk8;
    f32x4 acc[2] = {};
    #pragma unroll
    for (int kk = 0; kk < 9; ++kk) {
      bf16x8 bfv = *(const bf16x8*)(wp + kk*32);
      #pragma unroll
      for (int mi = 0; mi < 2; ++mi) {
        bf16x8 af = *(const bf16x8*)&Hs[mi*16 + l16][kk*32 + lk8];
        acc[mi] = __builtin_amdgcn_mfma_f32_16x16x32_bf16(af, bfv, acc[mi], 0, 0, 0);
      }
    }
    float b2 = j.bias2[col];
    float lw = j.law[col];
    #pragma unroll
    for (int mi = 0; mi < 2; ++mi)
      #pragma unroll
      for (int r = 0; r < 4; ++r) {
        int row = r0 + mi*16 + ((lane >> 4) << 2) + r;
        size_t off = (size_t)row * D_ + col;
        float al  = acc[mi][r] + b2;
        float xcv = j.A[off];
        float xiv = j.xi[off];
        j.xn[off] = xcv + al * hi + sq * xiv;
        float df = xcv - lw;
        fp[mi][r] += df * df + al * al;
      }
  }
  #pragma unroll
  for (int mi = 0; mi < 2; ++mi)
    #pragma unroll
    for (int r = 0; r < 4; ++r) {
      float s = fp[mi][r];
      s += __shfl_xor(s, 1); s += __shfl_xor(s, 2);
      s += __shfl_xor(s, 4); s += __shfl_xor(s, 8);
      if (l16 == 0)
        atomicAdd(&j.vacc[r0 + mi*16 + ((lane >> 4) << 2) + r], -0.5f * hi * s);
    }
}

__global__ __launch_bounds__(256) void multi(Pack p) {
  __shared__ char smem[SMEM_BYTES] __attribute__((aligned(16)));
  int b = blockIdx.x;
  int k = p.njobs - 1;
  while (k > 0 && b < p.j[k].t0) --k;
  const Job& j = p.j[k];
  int u = b - j.t0;
  if (j.kind == 0) {
    run_tile(j, u, p.invB, smem);
  } else if (j.kind == 3) {
    run_fused(j, u, smem);
  } else {
    // v0 finalize: v[r] = relu(BN1(yraw[r]))
    int r = u * 256 + threadIdx.x;
    float mu  = j.asum[0] * p.invB;
    float var = j.asq[0] * p.invB - mu * mu;
    float tt  = j.g[0] * (j.A[r] - mu) * rsqrtf(var + EPSF) + j.be[0];
    j.C[r] = fmaxf(tt, 0.f);
  }
}

// transpose + cast: out[s][n][k] = in[s][k][n] (k<K), zero-pad to Kp
__global__ __launch_bounds__(256) void wconv(const float* __restrict__ in, bf16_t* __restrict__ out,
                                             int K, int N, int Kp, int total) {
  for (int idx = blockIdx.x * 256 + threadIdx.x; idx < total; idx += gridDim.x * 256) {
    int k = idx % Kp; int rest = idx / Kp; int n = rest % N; int s = rest / N;
    float v = (k < K) ? in[((size_t)s * K + k) * N + n] : 0.f;
    out[idx] = (bf16_t)v;
  }
}

__global__ __launch_bounds__(256) void vadd(float* __restrict__ v, const float* __restrict__ vacc, int M) {
  int r = blockIdx.x * 256 + threadIdx.x;
  if (r < M) v[r] += vacc[r];
}

extern "C" void kernel_launch(void* const* d_in, const int* in_sizes, int n_in,
                              void* d_out, int out_size, void* d_ws, size_t ws_size,
                              hipStream_t stream) {
  const float* x    = (const float*)d_in[0];
  const float* W1   = (const float*)d_in[1];
  const float* b1   = (const float*)d_in[2];
  const float* g1   = (const float*)d_in[3];
  const float* be1  = (const float*)d_in[4];
  const float* W2   = (const float*)d_in[5];
  const float* b2   = (const float*)d_in[6];
  const float* g2   = (const float*)d_in[7];
  const float* be2  = (const float*)d_in[8];
  const float* W3   = (const float*)d_in[9];
  const float* b3   = (const float*)d_in[10];
  const float* vW1  = (const float*)d_in[11];
  const float* vb1  = (const float*)d_in[12];
  const float* vg1  = (const float*)d_in[13];
  const float* vbe1 = (const float*)d_in[14];
  const float* vW2  = (const float*)d_in[15];
  const float* vb2  = (const float*)d_in[16];
  const float* vg2  = (const float*)d_in[17];
  const float* vbe2 = (const float*)d_in[18];
  const float* vW3  = (const float*)d_in[19];
  const float* vb3  = (const float*)d_in[20];
  const float* vg3  = (const float*)d_in[21];
  const float* vbe3 = (const float*)d_in[22];
  const float* aW1  = (const float*)d_in[23];
  const float* ab1  = (const float*)d_in[24];
  const float* aW2  = (const float*)d_in[25];
  const float* ab2  = (const float*)d_in[26];
  const float* law  = (const float*)d_in[27];
  const float* tg   = (const float*)d_in[28];
  const float* xi   = (const float*)d_in[29];

  float* out    = (float*)d_out;
  float* v_out  = out;
  float* xf_out = out + B_;
  float* path   = out + B_ + (size_t)B_ * D_;

  float* ws   = (float*)d_ws;
  float* h1a  = ws;
  float* h1b  = h1a + (size_t)B_ * HP;
  float* h2a  = h1b + (size_t)B_ * HP;
  float* h2b  = h2a + (size_t)B_ * HP;
  float* hv1  = h2b + (size_t)B_ * HP;
  float* hv2  = hv1 + (size_t)B_ * HP;
  float* yraw = hv2 + (size_t)B_ * HP;
  float* stats = yraw + B_;
  const int NSLOT = 2 * S_ + 3;
  float* vacc = stats + (size_t)NSLOT * 2 * HP;

  bf16_t* wbuf = (bf16_t*)(vacc + B_);
  bf16_t* W1t  = wbuf;                                   // [50][266][256]
  bf16_t* W2t  = W1t + (size_t)S_ * H_ * 256;            // [50][266][320]
  bf16_t* W3t  = W2t + (size_t)S_ * H_ * 320;            // [50][256][320]
  bf16_t* aW1t = W3t + (size_t)S_ * 256 * 320;           // [266][256]
  bf16_t* aW2t = aW1t + (size_t)H_ * 256;                // [256][320]
  bf16_t* vW1t = aW2t + (size_t)256 * 320;               // [266][256]
  bf16_t* vW2t = vW1t + (size_t)H_ * 256;                // [266][320]
  bf16_t* vW3t = vW2t + (size_t)H_ * 320;                // [1][320]

  auto ssum = [&](int s) { return stats + (size_t)s * 2 * HP; };
  auto ssq  = [&](int s) { return stats + (size_t)s * 2 * HP + HP; };

  const float invB = 1.0f / (float)B_;

  hipMemsetAsync(stats, 0, ((size_t)NSLOT * 2 * HP + B_) * sizeof(float), stream);
  hipMemcpyAsync(path, x, (size_t)B_ * D_ * sizeof(float), hipMemcpyDeviceToDevice, stream);

  dim3 blk(256);
  // weight transpose+cast
  wconv<<<dim3(1024), blk, 0, stream>>>(W1,       W1t,  256, H_,  256, S_ * H_ * 256);
  wconv<<<dim3(1024), blk, 0, stream>>>(W2,       W2t,  H_,  H_,  320, S_ * H_ * 320);
  wconv<<<dim3(1024), blk, 0, stream>>>(W3,       W3t,  H_,  256, 320, S_ * 256 * 320);
  wconv<<<dim3(256),  blk, 0, stream>>>(aW1 + H_, aW1t, 256, H_,  256, H_ * 256);
  wconv<<<dim3(256),  blk, 0, stream>>>(aW2,      aW2t, H_,  256, 320, 256 * 320);
  wconv<<<dim3(256),  blk, 0, stream>>>(vW1,      vW1t, 256, H_,  256, H_ * 256);
  wconv<<<dim3(256),  blk, 0, stream>>>(vW2,      vW2t, H_,  H_,  320, H_ * 320);
  wconv<<<dim3(2),    blk, 0, stream>>>(vW3,      vW3t, H_,  1,   320, 320);

  // ---- job builders ----
  auto G = [&](const float* A, int lda, int Ka,
               const float* g, const float* be, const float* as, const float* aq, int bnA,
               const bf16_t* Wt, int ldw, const float* bias,
               float* C, int ldc, int N, int relu,
               float* su, float* sq2, int mode, int tidx, const float* xii) -> Job {
    Job j; memset(&j, 0, sizeof(j));
    j.kind = 0; j.A = A; j.lda = lda; j.Ka = Ka;
    j.g = g; j.be = be; j.asum = as; j.asq = aq; j.bnA = bnA;
    j.Wt = Wt; j.ldw = ldw; j.bias = bias;
    j.C = C; j.ldc = ldc; j.N = N; j.relu = relu;
    j.ssum = su; j.ssq = sq2; j.mode = mode; j.tidx = tidx;
    j.tg = tg; j.xi = xii; j.vacc = vacc;
    return j;
  };
  auto tilesOf = [&](const Job& j) -> int {
    if (j.kind == 0) return (B_ / BM) * ((j.N + BN - 1) >> 6);
    if (j.kind == 3) return FXT;
    return 16;
  };
  auto launch = [&](Job* js, int n) {
    Pack p; memset(&p, 0, sizeof(p));
    int tot = 0;
    for (int k = 0; k < n; ++k) { p.j[k] = js[k]; p.j[k].t0 = tot; tot += tilesOf(js[k]); }
    p.njobs = n; p.invB = invB;
    multi<<<dim3(tot), blk, 0, stream>>>(p);
  };

  // v0 jobs
  Job jv1 = G(x,   D_, D_, nullptr, nullptr, nullptr, nullptr, 0, vW1t, 256, vb1, hv1, HP, H_, 0, ssum(100), ssq(100), 0, 0, nullptr);
  Job jv2 = G(hv1, HP, H_, vg1, vbe1, ssum(100), ssq(100), 1,   vW2t, 320, vb2, hv2, HP, H_, 0, ssum(101), ssq(101), 0, 0, nullptr);
  Job jv3 = G(hv2, HP, H_, vg2, vbe2, ssum(101), ssq(101), 1,   vW3t, 320, vb3, yraw, 1, 1,  0, ssum(102), ssq(102), 0, 0, nullptr);
  Job jfin; memset(&jfin, 0, sizeof(jfin));
  jfin.kind = 2; jfin.A = yraw; jfin.g = vg3; jfin.be = vbe3;
  jfin.asum = ssum(102); jfin.asq = ssq(102); jfin.C = v_out;

  auto mkFX = [&](int i) -> Job {
    Job j; memset(&j, 0, sizeof(j));
    j.kind = 3;
    j.A    = path + (size_t)i * B_ * D_;
    j.xn   = path + (size_t)(i + 1) * B_ * D_;
    j.xi   = xi + (size_t)i * B_ * D_;
    j.law  = law + (size_t)i * D_;
    j.Wt   = aW1t; j.Wt2 = aW2t;
    j.bias = ab1;  j.bias2 = ab2; j.trow = aW1;
    j.tg = tg; j.tidx = i; j.vacc = vacc;
    return j;
  };
  auto mkJA = [&](int i) -> Job {
    return G(path + (size_t)i * B_ * D_, D_, D_, nullptr, nullptr, nullptr, nullptr, 0,
             W1t + (size_t)i * H_ * 256, 256, b1 + (size_t)i * H_,
             (i & 1) ? h1b : h1a, HP, H_, 0, ssum(2*i), ssq(2*i), 0, i, nullptr);
  };
  auto mkJC = [&](int i) -> Job {
    return G((i & 1) ? h1b : h1a, HP, H_, g1 + (size_t)i * H_, be1 + (size_t)i * H_, ssum(2*i), ssq(2*i), 1,
             W2t + (size_t)i * H_ * 320, 320, b2 + (size_t)i * H_,
             (i & 1) ? h2b : h2a, HP, H_, 0, ssum(2*i+1), ssq(2*i+1), 0, i, nullptr);
  };
  auto mkJD = [&](int i) -> Job {
    return G((i & 1) ? h2b : h2a, HP, H_, g2 + (size_t)i * H_, be2 + (size_t)i * H_, ssum(2*i+1), ssq(2*i+1), 1,
             W3t + (size_t)i * 256 * 320, 320, b3 + (size_t)i * D_,
             nullptr, 0, D_, 0, nullptr, nullptr, 2, i, xi + (size_t)i * B_ * D_);
  };

  // prologue
  { Job js[1] = { jv1 };                               launch(js, 1); }
  { Job js[3] = { mkFX(0), mkJA(0), jv2 };             launch(js, 3); }
  { Job js[4] = { mkFX(1), mkJA(1), mkJC(0), jv3 };    launch(js, 4); }
  { Job js[5] = { mkFX(2), mkJA(2), mkJC(1), mkJD(0), jfin }; launch(js, 5); }
  // steady scan
  for (int i = 3; i < S_; ++i) {
    Job js[4] = { mkFX(i), mkJA(i), mkJC(i-1), mkJD(i-2) };
    launch(js, 4);
  }
  // tail
  { Job js[2] = { mkJC(S_-1), mkJD(S_-2) };            launch(js, 2); }
  { Job js[1] = { mkJD(S_-1) };                        launch(js, 1); }
  vadd<<<dim3(16), blk, 0, stream>>>(v_out, vacc, B_);

  hipMemcpyAsync(xf_out, path + (size_t)S_ * B_ * D_,
                 (size_t)B_ * D_ * sizeof(float), hipMemcpyDeviceToDevice, stream);
}